// Round 1
// 16357.481 us; speedup vs baseline: 1.2994x; 1.2994x over previous
//
#include <hip/hip_runtime.h>
#include <stdint.h>

#define B_  64
#define T_  2048
#define I_  256
#define H_  512
#define NG  4      // batch groups (16 batch each)
#define NP  8      // WGs per group, each owns HS h-elements
#define HS  64

typedef __attribute__((ext_vector_type(8))) short  short8;
typedef __attribute__((ext_vector_type(4))) float  floatx4;
typedef unsigned long long u64;

__device__ __forceinline__ unsigned short f2bf(float f) {
    unsigned u = __float_as_uint(f);
    u = (u + 0x7fffu + ((u >> 16) & 1u)) >> 16;   // RNE
    return (unsigned short)u;
}

__device__ __forceinline__ short8 ld8_bf(const float* p) {
    floatx4 a = *(const floatx4*)p;
    floatx4 c = *(const floatx4*)(p + 4);
    short8 r;
    r[0] = (short)f2bf(a[0]); r[1] = (short)f2bf(a[1]);
    r[2] = (short)f2bf(a[2]); r[3] = (short)f2bf(a[3]);
    r[4] = (short)f2bf(c[0]); r[5] = (short)f2bf(c[1]);
    r[6] = (short)f2bf(c[2]); r[7] = (short)f2bf(c[3]);
    return r;
}

__device__ __forceinline__ float sigf(float x) { return 1.f / (1.f + __expf(-x)); }
__device__ __forceinline__ float tanh_(float x) { return 2.f * sigf(2.f * x) - 1.f; }

__global__ __launch_bounds__(256, 1) void gru_persist(
    const float* __restrict__ xs, const float* __restrict__ w_ih,
    const float* __restrict__ w_hh, const float* __restrict__ b,
    const float* __restrict__ b_n, float* __restrict__ out,
    unsigned* __restrict__ flags, unsigned short* __restrict__ hpub)
{
    const int tid  = threadIdx.x;
    const int wv   = tid >> 6;          // wave 0..3 -> h-tile within slice
    const int lane = tid & 63;
    const int q    = lane >> 4;         // quad 0..3
    const int c    = lane & 15;         // col: batch within group / row within A-tile
    const int g    = blockIdx.x & (NG - 1);
    const int p    = blockIdx.x >> 2;   // 0..7 slice owner within group
    const int hbase = p * HS + wv * 16; // this wave's 16 h-rows
    const int batch = g * 16 + c;

    // ---- weight preload: A-fragments resident in VGPRs/AGPRs ----
    short8 whh[3][16];  // 3 gates x 16 k-tiles over H=512
    short8 wih[3][8];   // 3 gates x  8 k-tiles over I=256
#pragma unroll
    for (int gate = 0; gate < 3; ++gate) {
        const float* wr = w_hh + (size_t)(gate * H_ + hbase + c) * H_ + q * 8;
#pragma unroll
        for (int kt = 0; kt < 16; ++kt) whh[gate][kt] = ld8_bf(wr + kt * 32);
        const float* wi = w_ih + (size_t)(gate * H_ + hbase + c) * I_ + q * 8;
#pragma unroll
        for (int kt = 0; kt < 8; ++kt)  wih[gate][kt] = ld8_bf(wi + kt * 32);
    }
    float br[4], bz[4], bni[4], bnn[4];
#pragma unroll
    for (int i = 0; i < 4; ++i) {
        int j = hbase + q * 4 + i;
        br[i]  = b[j];
        bz[i]  = b[H_ + j];
        bni[i] = b[2 * H_ + j];
        bnn[i] = b_n[j];
    }
    float hown[4] = {0.f, 0.f, 0.f, 0.f};   // fp32 master h at (row=q*4+i, col=c)

    const int myflag = (g * NP + p) * 16;

    for (int t = 0; t < T_; ++t) {
        // ---- input-gate GEMM: independent of h, overlaps peer wait ----
        const float* xrow = xs + ((size_t)batch * T_ + t) * I_ + q * 8;
        short8 bx[8];
#pragma unroll
        for (int kt = 0; kt < 8; ++kt) bx[kt] = ld8_bf(xrow + kt * 32);

        floatx4 accr  = {br[0],  br[1],  br[2],  br[3]};
        floatx4 accz  = {bz[0],  bz[1],  bz[2],  bz[3]};
        floatx4 accni = {bni[0], bni[1], bni[2], bni[3]};
        floatx4 accnh = {0.f, 0.f, 0.f, 0.f};
#pragma unroll
        for (int kt = 0; kt < 8; ++kt) {
            accr  = __builtin_amdgcn_mfma_f32_16x16x32_bf16(wih[0][kt], bx[kt], accr,  0, 0, 0);
            accz  = __builtin_amdgcn_mfma_f32_16x16x32_bf16(wih[1][kt], bx[kt], accz,  0, 0, 0);
            accni = __builtin_amdgcn_mfma_f32_16x16x32_bf16(wih[2][kt], bx[kt], accni, 0, 0, 0);
        }

        // h read base for this step's parity (address math off the critical path)
        const char* hb = (const char*)(hpub + ((size_t)(t & 1) * B_ + batch) * H_) + q * 16;

        // ---- wait for all peers to have published h_t (coherent dword loads,
        //      no cache-wide fence) ----
        if (tid < NP) {
            while ((int)__hip_atomic_load(&flags[(g * NP + tid) * 16],
                       __ATOMIC_RELAXED, __HIP_MEMORY_SCOPE_AGENT) < t)
                __builtin_amdgcn_s_sleep(1);
        }
        __syncthreads();
        asm volatile("" ::: "memory");  // compiler barrier only (no buffer_inv)

        // ---- recurrent GEMM ----
        // Prefetch ALL 16 h fragments as pipelined coherent 16B loads (sc0 sc1
        // = same visibility as agent-scope atomics), ONE latency round trip
        // instead of 16 serialized load->mfma->load chains.
        short8 bh[16];
#pragma unroll
        for (int kt = 0; kt < 16; ++kt) {
            asm volatile("global_load_dwordx4 %0, %1, off offset:%2 sc0 sc1"
                         : "=&v"(bh[kt]) : "v"(hb), "n"(kt * 64) : "memory");
        }
        asm volatile("s_waitcnt vmcnt(0)" ::: "memory");
        __builtin_amdgcn_sched_barrier(0);   // pin MFMAs behind the waitcnt (ERRATA #18)

#pragma unroll
        for (int kt = 0; kt < 16; ++kt) {
            accr  = __builtin_amdgcn_mfma_f32_16x16x32_bf16(whh[0][kt], bh[kt], accr,  0, 0, 0);
            accz  = __builtin_amdgcn_mfma_f32_16x16x32_bf16(whh[1][kt], bh[kt], accz,  0, 0, 0);
            accnh = __builtin_amdgcn_mfma_f32_16x16x32_bf16(whh[2][kt], bh[kt], accnh, 0, 0, 0);
        }

        // ---- gates (lane-local) ----
#pragma unroll
        for (int i = 0; i < 4; ++i) {
            float r = sigf(accr[i]);
            float z = sigf(accz[i]);
            float n = tanh_(accni[i] + r * (accnh[i] + bnn[i]));
            hown[i] = n + z * (hown[i] - n);
        }

        if (t + 1 < T_) {
            // publish own slice as one coherent 8B store per lane
            u64 pk = (u64)f2bf(hown[0])
                   | ((u64)f2bf(hown[1]) << 16)
                   | ((u64)f2bf(hown[2]) << 32)
                   | ((u64)f2bf(hown[3]) << 48);
            u64* dst = (u64*)(hpub + ((size_t)((t + 1) & 1) * B_ + batch) * H_ + hbase + q * 4);
            __hip_atomic_store(dst, pk, __ATOMIC_RELAXED, __HIP_MEMORY_SCOPE_AGENT);
            // order: h-store ack from coherence point BEFORE flag store
            asm volatile("s_waitcnt vmcnt(0)" ::: "memory");
            __syncthreads();
            if (tid == 0)
                __hip_atomic_store(&flags[myflag], (unsigned)(t + 1),
                                   __ATOMIC_RELAXED, __HIP_MEMORY_SCOPE_AGENT);
        }
    }

    // ---- final h (fp32) ----
    floatx4 o = {hown[0], hown[1], hown[2], hown[3]};
    *(floatx4*)(out + (size_t)batch * H_ + hbase + q * 4) = o;
}

extern "C" void kernel_launch(void* const* d_in, const int* in_sizes, int n_in,
                              void* d_out, int out_size, void* d_ws, size_t ws_size,
                              hipStream_t stream) {
    (void)in_sizes; (void)n_in; (void)out_size; (void)ws_size;
    const float* xs   = (const float*)d_in[0];
    const float* w_ih = (const float*)d_in[1];
    const float* w_hh = (const float*)d_in[2];
    const float* b    = (const float*)d_in[3];
    const float* b_n  = (const float*)d_in[4];
    float* out = (float*)d_out;

    unsigned*       flags = (unsigned*)d_ws;                       // 2KB used
    unsigned short* hpub  = (unsigned short*)((char*)d_ws + 4096); // 2*64*512*2 = 128KB

    // zero flags + h double-buffer (ws is poisoned 0xAA before every call)
    (void)hipMemsetAsync(d_ws, 0, 4096 + 2 * B_ * H_ * sizeof(unsigned short), stream);

    gru_persist<<<NG * NP, 256, 0, stream>>>(xs, w_ih, w_hh, b, b_n, out, flags, hpub);
}

// Round 2
// 10044.786 us; speedup vs baseline: 2.1160x; 1.6285x over previous
//
#include <hip/hip_runtime.h>
#include <stdint.h>

#define B_  64
#define T_  2048
#define I_  256
#define H_  512
#define NG  4      // batch groups (16 batch each)
#define NP  8      // WGs per group, each owns HS h-elements
#define HS  64

typedef __attribute__((ext_vector_type(8))) short  short8;
typedef __attribute__((ext_vector_type(4))) float  floatx4;
typedef unsigned long long u64;

// ws layout:
//   [0, 8KB)      : per-wave step flags, 128 waves x 64B spacing
//   [8KB, 16KB)   : per-wave conversion-done flags (xsb pre-pass)
//   [16KB, 144KB) : hpub, 2 x 64 x 512 bf16 (h double buffer)
//   [144KB, +64MB): xsb, xs pre-converted to bf16, tiled [t][g][kt][(q,c)*16B]
#define FLAGS_DW   0
#define CFLAGS_DW  2048
#define HPUB_OFF   16384
#define XSB_OFF    147456
#define XSB_BYTES  ((size_t)T_ * NG * 8 * 1024)   // 64 MB

__device__ __forceinline__ unsigned short f2bf(float f) {
    unsigned u = __float_as_uint(f);
    u = (u + 0x7fffu + ((u >> 16) & 1u)) >> 16;   // RNE
    return (unsigned short)u;
}

__device__ __forceinline__ short8 ld8_bf(const float* p) {
    floatx4 a = *(const floatx4*)p;
    floatx4 c = *(const floatx4*)(p + 4);
    short8 r;
    r[0] = (short)f2bf(a[0]); r[1] = (short)f2bf(a[1]);
    r[2] = (short)f2bf(a[2]); r[3] = (short)f2bf(a[3]);
    r[4] = (short)f2bf(c[0]); r[5] = (short)f2bf(c[1]);
    r[6] = (short)f2bf(c[2]); r[7] = (short)f2bf(c[3]);
    return r;
}

__device__ __forceinline__ float sigf(float x) { return 1.f / (1.f + __expf(-x)); }
__device__ __forceinline__ float tanh_(float x) { return 2.f * sigf(2.f * x) - 1.f; }

__global__ __launch_bounds__(256, 1) void gru_persist(
    const float* __restrict__ xs, const float* __restrict__ w_ih,
    const float* __restrict__ w_hh, const float* __restrict__ b,
    const float* __restrict__ b_n, float* __restrict__ out,
    unsigned* __restrict__ flags, unsigned short* __restrict__ hpub,
    char* __restrict__ xsb, int use_xsb)
{
    const int tid  = threadIdx.x;
    const int wv   = tid >> 6;          // wave 0..3 -> h-tile within slice
    const int lane = tid & 63;
    const int q    = lane >> 4;         // quad 0..3
    const int c    = lane & 15;         // col: batch within group / row within A-tile
    const int g    = blockIdx.x & (NG - 1);
    const int p    = blockIdx.x >> 2;   // 0..7 slice owner within group
    const int hbase = p * HS + wv * 16; // this wave's 16 h-rows
    const int batch = g * 16 + c;

    // ---- weight preload: A-fragments resident in VGPRs/AGPRs ----
    short8 whh[3][16];  // 3 gates x 16 k-tiles over H=512
    short8 wih[3][8];   // 3 gates x  8 k-tiles over I=256
#pragma unroll
    for (int gate = 0; gate < 3; ++gate) {
        const float* wr = w_hh + (size_t)(gate * H_ + hbase + c) * H_ + q * 8;
#pragma unroll
        for (int kt = 0; kt < 16; ++kt) whh[gate][kt] = ld8_bf(wr + kt * 32);
        const float* wi = w_ih + (size_t)(gate * H_ + hbase + c) * I_ + q * 8;
#pragma unroll
        for (int kt = 0; kt < 8; ++kt)  wih[gate][kt] = ld8_bf(wi + kt * 32);
    }
    float br[4], bz[4], bni[4], bnn[4];
#pragma unroll
    for (int i = 0; i < 4; ++i) {
        int j = hbase + q * 4 + i;
        br[i]  = b[j];
        bz[i]  = b[H_ + j];
        bni[i] = b[2 * H_ + j];
        bnn[i] = b_n[j];
    }
    float hown[4] = {0.f, 0.f, 0.f, 0.f};   // fp32 master h at (row=q*4+i, col=c)

    // ---- xs -> bf16 pre-pass (one-time), tiled for 1KB/wave contiguous reads ----
    if (use_xsb) {
        for (int k = 0; k < T_ / 32; ++k) {
            int t = k * 32 + p * 4 + wv;   // each of the 32 group-waves owns T/32 rows
            const float* src = xs + ((size_t)batch * T_ + t) * I_ + q * 8;
            char* db  = xsb + (((size_t)t * NG + g) << 13) + ((q * 16 + c) << 4);
            char* db2 = db + 4096;
            short8 v0 = ld8_bf(src + 0 * 32);
            short8 v1 = ld8_bf(src + 1 * 32);
            short8 v2 = ld8_bf(src + 2 * 32);
            short8 v3 = ld8_bf(src + 3 * 32);
            short8 v4 = ld8_bf(src + 4 * 32);
            short8 v5 = ld8_bf(src + 5 * 32);
            short8 v6 = ld8_bf(src + 6 * 32);
            short8 v7 = ld8_bf(src + 7 * 32);
            asm volatile("global_store_dwordx4 %0, %1, off sc0 sc1"             :: "v"(db),  "v"(v0) : "memory");
            asm volatile("global_store_dwordx4 %0, %1, off offset:1024 sc0 sc1" :: "v"(db),  "v"(v1) : "memory");
            asm volatile("global_store_dwordx4 %0, %1, off offset:2048 sc0 sc1" :: "v"(db),  "v"(v2) : "memory");
            asm volatile("global_store_dwordx4 %0, %1, off offset:3072 sc0 sc1" :: "v"(db),  "v"(v3) : "memory");
            asm volatile("global_store_dwordx4 %0, %1, off sc0 sc1"             :: "v"(db2), "v"(v4) : "memory");
            asm volatile("global_store_dwordx4 %0, %1, off offset:1024 sc0 sc1" :: "v"(db2), "v"(v5) : "memory");
            asm volatile("global_store_dwordx4 %0, %1, off offset:2048 sc0 sc1" :: "v"(db2), "v"(v6) : "memory");
            asm volatile("global_store_dwordx4 %0, %1, off offset:3072 sc0 sc1" :: "v"(db2), "v"(v7) : "memory");
        }
        asm volatile("s_waitcnt vmcnt(0)" ::: "memory");
        if (lane == 0) {
            unsigned one = 1;
            unsigned* cfa = flags + CFLAGS_DW + ((g * 32 + p * 4 + wv) << 4);
            asm volatile("global_store_dword %0, %1, off sc0 sc1" :: "v"(cfa), "v"(one) : "memory");
        }
        // gate: wait for all 32 group waves to finish converting
        const unsigned* cfp = flags + CFLAGS_DW + ((g * 32 + (lane & 31)) << 4);
        for (;;) {
            unsigned cv;
            asm volatile("global_load_dword %0, %1, off sc0 sc1" : "=v"(cv) : "v"(cfp) : "memory");
            asm volatile("s_waitcnt vmcnt(0)" ::: "memory");
            if (__all(cv == 1u)) break;
            __builtin_amdgcn_s_sleep(1);
        }
    }

    const unsigned* fp   = flags + ((g * 32 + (lane & 31)) << 4);   // peer wave flags
    unsigned*       myfa = flags + ((g * 32 + p * 4 + wv) << 4);    // own flag

    short8 bx[8];
    if (use_xsb) {  // prefetch x(t=0)
        const char* xb  = xsb + (((size_t)0 * NG + g) << 13) + ((q * 16 + c) << 4);
        const char* xb2 = xb + 4096;
        asm volatile("global_load_dwordx4 %0, %1, off sc0 sc1"             : "=&v"(bx[0]) : "v"(xb)  : "memory");
        asm volatile("global_load_dwordx4 %0, %1, off offset:1024 sc0 sc1" : "=&v"(bx[1]) : "v"(xb)  : "memory");
        asm volatile("global_load_dwordx4 %0, %1, off offset:2048 sc0 sc1" : "=&v"(bx[2]) : "v"(xb)  : "memory");
        asm volatile("global_load_dwordx4 %0, %1, off offset:3072 sc0 sc1" : "=&v"(bx[3]) : "v"(xb)  : "memory");
        asm volatile("global_load_dwordx4 %0, %1, off sc0 sc1"             : "=&v"(bx[4]) : "v"(xb2) : "memory");
        asm volatile("global_load_dwordx4 %0, %1, off offset:1024 sc0 sc1" : "=&v"(bx[5]) : "v"(xb2) : "memory");
        asm volatile("global_load_dwordx4 %0, %1, off offset:2048 sc0 sc1" : "=&v"(bx[6]) : "v"(xb2) : "memory");
        asm volatile("global_load_dwordx4 %0, %1, off offset:3072 sc0 sc1" : "=&v"(bx[7]) : "v"(xb2) : "memory");
    }

    for (int t = 0; t < T_; ++t) {
        if (!use_xsb) {
            // fallback: load+convert x(t) before the poll (overlaps peers' publish)
            const float* xrow = xs + ((size_t)batch * T_ + t) * I_ + q * 8;
#pragma unroll
            for (int kt = 0; kt < 8; ++kt) bx[kt] = ld8_bf(xrow + kt * 32);
        }

        // ---- poll all 32 producer waves of this group (all 64 lanes) ----
        // The vmcnt(0) inside the poll also drains the prefetched bx loads.
        for (;;) {
            int fv;
            asm volatile("global_load_dword %0, %1, off sc0 sc1" : "=v"(fv) : "v"(fp) : "memory");
            asm volatile("s_waitcnt vmcnt(0)" ::: "memory");
            if (__all(fv >= t)) break;
            __builtin_amdgcn_s_sleep(1);
        }
        __builtin_amdgcn_sched_barrier(0);

        // ---- issue h prefetch NOW; latency hides under the input-gate MFMAs ----
        short8 bh[16];
        const char* hb = (const char*)(hpub + ((size_t)(t & 1) * B_ + batch) * H_) + q * 16;
#pragma unroll
        for (int kt = 0; kt < 16; ++kt) {
            asm volatile("global_load_dwordx4 %0, %1, off offset:%2 sc0 sc1"
                         : "=&v"(bh[kt]) : "v"(hb), "n"(kt * 64) : "memory");
        }

        // ---- input-gate GEMM (independent of h) ----
        floatx4 accr  = {br[0],  br[1],  br[2],  br[3]};
        floatx4 accz  = {bz[0],  bz[1],  bz[2],  bz[3]};
        floatx4 accni = {bni[0], bni[1], bni[2], bni[3]};
        floatx4 accnh = {0.f, 0.f, 0.f, 0.f};
#pragma unroll
        for (int kt = 0; kt < 8; ++kt) {
            accr  = __builtin_amdgcn_mfma_f32_16x16x32_bf16(wih[0][kt], bx[kt], accr,  0, 0, 0);
            accz  = __builtin_amdgcn_mfma_f32_16x16x32_bf16(wih[1][kt], bx[kt], accz,  0, 0, 0);
            accni = __builtin_amdgcn_mfma_f32_16x16x32_bf16(wih[2][kt], bx[kt], accni, 0, 0, 0);
        }

        asm volatile("s_waitcnt vmcnt(0)" ::: "memory");
        __builtin_amdgcn_sched_barrier(0);   // pin MFMAs behind the waitcnt (ERRATA #18)

        // ---- recurrent GEMM ----
#pragma unroll
        for (int kt = 0; kt < 16; ++kt) {
            accr  = __builtin_amdgcn_mfma_f32_16x16x32_bf16(whh[0][kt], bh[kt], accr,  0, 0, 0);
            accz  = __builtin_amdgcn_mfma_f32_16x16x32_bf16(whh[1][kt], bh[kt], accz,  0, 0, 0);
            accnh = __builtin_amdgcn_mfma_f32_16x16x32_bf16(whh[2][kt], bh[kt], accnh, 0, 0, 0);
        }

        // ---- gates (lane-local) ----
#pragma unroll
        for (int i = 0; i < 4; ++i) {
            float r = sigf(accr[i]);
            float z = sigf(accz[i]);
            float n = tanh_(accni[i] + r * (accnh[i] + bnn[i]));
            hown[i] = n + z * (hown[i] - n);
        }

        if (t + 1 < T_) {
            // publish own slice (8B atomic store), overlap the ack with next-x
            // prefetch, then raise own flag. No intra-WG barriers anywhere.
            u64 pk = (u64)f2bf(hown[0])
                   | ((u64)f2bf(hown[1]) << 16)
                   | ((u64)f2bf(hown[2]) << 32)
                   | ((u64)f2bf(hown[3]) << 48);
            u64* dst = (u64*)(hpub + ((size_t)((t + 1) & 1) * B_ + batch) * H_ + hbase + q * 4);
            __builtin_amdgcn_sched_barrier(0);
            asm volatile("global_store_dwordx2 %0, %1, off sc0 sc1" :: "v"(dst), "v"(pk) : "memory");
            if (use_xsb) {
                const char* xb  = xsb + (((size_t)(t + 1) * NG + g) << 13) + ((q * 16 + c) << 4);
                const char* xb2 = xb + 4096;
                asm volatile("global_load_dwordx4 %0, %1, off sc0 sc1"             : "=&v"(bx[0]) : "v"(xb)  : "memory");
                asm volatile("global_load_dwordx4 %0, %1, off offset:1024 sc0 sc1" : "=&v"(bx[1]) : "v"(xb)  : "memory");
                asm volatile("global_load_dwordx4 %0, %1, off offset:2048 sc0 sc1" : "=&v"(bx[2]) : "v"(xb)  : "memory");
                asm volatile("global_load_dwordx4 %0, %1, off offset:3072 sc0 sc1" : "=&v"(bx[3]) : "v"(xb)  : "memory");
                asm volatile("global_load_dwordx4 %0, %1, off sc0 sc1"             : "=&v"(bx[4]) : "v"(xb2) : "memory");
                asm volatile("global_load_dwordx4 %0, %1, off offset:1024 sc0 sc1" : "=&v"(bx[5]) : "v"(xb2) : "memory");
                asm volatile("global_load_dwordx4 %0, %1, off offset:2048 sc0 sc1" : "=&v"(bx[6]) : "v"(xb2) : "memory");
                asm volatile("global_load_dwordx4 %0, %1, off offset:3072 sc0 sc1" : "=&v"(bx[7]) : "v"(xb2) : "memory");
            }
            // vmcnt(0): h-store acked at coherence point before flag goes up
            // (also spill-proof: any compiler-injected vmem drains too)
            asm volatile("s_waitcnt vmcnt(0)" ::: "memory");
            __builtin_amdgcn_sched_barrier(0);
            if (lane == 0) {
                unsigned nv = (unsigned)(t + 1);
                asm volatile("global_store_dword %0, %1, off sc0 sc1" :: "v"(myfa), "v"(nv) : "memory");
            }
        }
    }

    // ---- final h (fp32) ----
    floatx4 o = {hown[0], hown[1], hown[2], hown[3]};
    *(floatx4*)(out + (size_t)batch * H_ + hbase + q * 4) = o;
}

extern "C" void kernel_launch(void* const* d_in, const int* in_sizes, int n_in,
                              void* d_out, int out_size, void* d_ws, size_t ws_size,
                              hipStream_t stream) {
    (void)in_sizes; (void)n_in; (void)out_size;
    const float* xs   = (const float*)d_in[0];
    const float* w_ih = (const float*)d_in[1];
    const float* w_hh = (const float*)d_in[2];
    const float* b    = (const float*)d_in[3];
    const float* b_n  = (const float*)d_in[4];
    float* out = (float*)d_out;

    unsigned*       flags = (unsigned*)d_ws;
    unsigned short* hpub  = (unsigned short*)((char*)d_ws + HPUB_OFF);
    char*           xsb   = (char*)d_ws + XSB_OFF;
    const int use_xsb = (ws_size >= (size_t)XSB_OFF + XSB_BYTES) ? 1 : 0;

    // zero flags + cflags + h double-buffer (ws is poisoned 0xAA before every call)
    (void)hipMemsetAsync(d_ws, 0, XSB_OFF, stream);

    gru_persist<<<NG * NP, 256, 0, stream>>>(xs, w_ih, w_hh, b, b_n, out,
                                             flags, hpub, xsb, use_xsb);
}

// Round 3
// 7455.288 us; speedup vs baseline: 2.8510x; 1.3473x over previous
//
#include <hip/hip_runtime.h>
#include <stdint.h>

#define B_  64
#define T_  2048
#define I_  256
#define H_  512
#define NG  4      // batch groups (16 batch each)
#define NP  8      // WGs per group, each owns HS h-elements
#define HS  64

typedef __attribute__((ext_vector_type(8))) short  short8;
typedef __attribute__((ext_vector_type(4))) float  floatx4;
typedef __attribute__((ext_vector_type(4))) unsigned uintx4;
typedef unsigned long long u64;

// ws layout:
//   [0, 8KB)        : (unused, legacy flags)
//   [8KB, 16KB)     : per-wave conversion-done flags (xsb pre-pass)
//   [16KB, 272KB)   : hpub32, 2 x 64 x 512 TAGGED u32: (bf16<<16)|step
//   [272KB, +64MB)  : xsb, xs pre-converted to bf16, tiled [t][g][...]
#define CFLAGS_DW  2048
#define HPUB32_OFF 16384
#define XSB_OFF    (16384 + 2 * B_ * H_ * 4)          // 278528
#define XSB_BYTES  ((size_t)T_ * NG * 8 * 1024)       // 64 MB

__device__ __forceinline__ unsigned short f2bf(float f) {
    unsigned u = __float_as_uint(f);
    u = (u + 0x7fffu + ((u >> 16) & 1u)) >> 16;   // RNE
    return (unsigned short)u;
}

__device__ __forceinline__ short8 ld8_bf(const float* p) {
    floatx4 a = *(const floatx4*)p;
    floatx4 c = *(const floatx4*)(p + 4);
    short8 r;
    r[0] = (short)f2bf(a[0]); r[1] = (short)f2bf(a[1]);
    r[2] = (short)f2bf(a[2]); r[3] = (short)f2bf(a[3]);
    r[4] = (short)f2bf(c[0]); r[5] = (short)f2bf(c[1]);
    r[6] = (short)f2bf(c[2]); r[7] = (short)f2bf(c[3]);
    return r;
}

__device__ __forceinline__ float sigf(float x) { return 1.f / (1.f + __expf(-x)); }
__device__ __forceinline__ float tanh_(float x) { return 2.f * sigf(2.f * x) - 1.f; }

__global__ __launch_bounds__(256, 1) void gru_persist(
    const float* __restrict__ xs, const float* __restrict__ w_ih,
    const float* __restrict__ w_hh, const float* __restrict__ b,
    const float* __restrict__ b_n, float* __restrict__ out,
    unsigned* __restrict__ flags, unsigned* __restrict__ hpub32,
    char* __restrict__ xsb, int use_xsb)
{
    const int tid  = threadIdx.x;
    const int wv   = tid >> 6;          // wave 0..3
    const int lane = tid & 63;
    const int q    = lane >> 4;         // quad 0..3
    const int c    = lane & 15;         // batch within group / MFMA col
    const int g    = blockIdx.x & (NG - 1);
    const int p    = blockIdx.x >> 2;   // slice owner within group
    const int hbase = p * HS + wv * 16; // this wave's 16 h-rows
    const int batch = g * 16 + c;

    // LDS: double-buffered packed-bf16 h tiles: [buf][kt=16][c=16 rows x 80B]
    __shared__ uintx4 smem[2][1280];    // 2 x 20480 B

    // ---- weight preload ----
    short8 whh[3][16];
    short8 wih[3][8];
#pragma unroll
    for (int gate = 0; gate < 3; ++gate) {
        const float* wr = w_hh + (size_t)(gate * H_ + hbase + c) * H_ + q * 8;
#pragma unroll
        for (int kt = 0; kt < 16; ++kt) whh[gate][kt] = ld8_bf(wr + kt * 32);
        const float* wi = w_ih + (size_t)(gate * H_ + hbase + c) * I_ + q * 8;
#pragma unroll
        for (int kt = 0; kt < 8; ++kt)  wih[gate][kt] = ld8_bf(wi + kt * 32);
    }
    float br[4], bz[4], bni[4], bnn[4];
#pragma unroll
    for (int i = 0; i < 4; ++i) {
        int j = hbase + q * 4 + i;
        br[i]  = b[j];
        bz[i]  = b[H_ + j];
        bni[i] = b[2 * H_ + j];
        bnn[i] = b_n[j];
    }
    float hown[4] = {0.f, 0.f, 0.f, 0.f};

    // ---- xs -> bf16 pre-pass (one-time) ----
    if (use_xsb) {
        for (int k = 0; k < T_ / 32; ++k) {
            int t = k * 32 + p * 4 + wv;
            const float* src = xs + ((size_t)batch * T_ + t) * I_ + q * 8;
            char* db  = xsb + (((size_t)t * NG + g) << 13) + ((q * 16 + c) << 4);
            char* db2 = db + 4096;
            short8 v0 = ld8_bf(src + 0 * 32);
            short8 v1 = ld8_bf(src + 1 * 32);
            short8 v2 = ld8_bf(src + 2 * 32);
            short8 v3 = ld8_bf(src + 3 * 32);
            short8 v4 = ld8_bf(src + 4 * 32);
            short8 v5 = ld8_bf(src + 5 * 32);
            short8 v6 = ld8_bf(src + 6 * 32);
            short8 v7 = ld8_bf(src + 7 * 32);
            asm volatile("global_store_dwordx4 %0, %1, off sc0 sc1"             :: "v"(db),  "v"(v0) : "memory");
            asm volatile("global_store_dwordx4 %0, %1, off offset:1024 sc0 sc1" :: "v"(db),  "v"(v1) : "memory");
            asm volatile("global_store_dwordx4 %0, %1, off offset:2048 sc0 sc1" :: "v"(db),  "v"(v2) : "memory");
            asm volatile("global_store_dwordx4 %0, %1, off offset:3072 sc0 sc1" :: "v"(db),  "v"(v3) : "memory");
            asm volatile("global_store_dwordx4 %0, %1, off sc0 sc1"             :: "v"(db2), "v"(v4) : "memory");
            asm volatile("global_store_dwordx4 %0, %1, off offset:1024 sc0 sc1" :: "v"(db2), "v"(v5) : "memory");
            asm volatile("global_store_dwordx4 %0, %1, off offset:2048 sc0 sc1" :: "v"(db2), "v"(v6) : "memory");
            asm volatile("global_store_dwordx4 %0, %1, off offset:3072 sc0 sc1" :: "v"(db2), "v"(v7) : "memory");
        }
        asm volatile("s_waitcnt vmcnt(0)" ::: "memory");
        if (lane == 0) {
            unsigned one = 1;
            unsigned* cfa = flags + CFLAGS_DW + ((g * 32 + p * 4 + wv) << 4);
            asm volatile("global_store_dword %0, %1, off sc0 sc1" :: "v"(cfa), "v"(one) : "memory");
        }
        const unsigned* cfp = flags + CFLAGS_DW + ((g * 32 + (lane & 31)) << 4);
        for (;;) {
            unsigned cv;
            asm volatile("global_load_dword %0, %1, off sc0 sc1" : "=v"(cv) : "v"(cfp) : "memory");
            asm volatile("s_waitcnt vmcnt(0)" ::: "memory");
            if (__all(cv == 1u)) break;
            __builtin_amdgcn_s_sleep(1);
        }
    }

    short8 bx[8];
    if (use_xsb) {  // prefetch x(t=0)
        const char* xb  = xsb + (((size_t)0 * NG + g) << 13) + ((q * 16 + c) << 4);
        const char* xb2 = xb + 4096;
        asm volatile("global_load_dwordx4 %0, %1, off sc0 sc1"             : "=&v"(bx[0]) : "v"(xb)  : "memory");
        asm volatile("global_load_dwordx4 %0, %1, off offset:1024 sc0 sc1" : "=&v"(bx[1]) : "v"(xb)  : "memory");
        asm volatile("global_load_dwordx4 %0, %1, off offset:2048 sc0 sc1" : "=&v"(bx[2]) : "v"(xb)  : "memory");
        asm volatile("global_load_dwordx4 %0, %1, off offset:3072 sc0 sc1" : "=&v"(bx[3]) : "v"(xb)  : "memory");
        asm volatile("global_load_dwordx4 %0, %1, off sc0 sc1"             : "=&v"(bx[4]) : "v"(xb2) : "memory");
        asm volatile("global_load_dwordx4 %0, %1, off offset:1024 sc0 sc1" : "=&v"(bx[5]) : "v"(xb2) : "memory");
        asm volatile("global_load_dwordx4 %0, %1, off offset:2048 sc0 sc1" : "=&v"(bx[6]) : "v"(xb2) : "memory");
        asm volatile("global_load_dwordx4 %0, %1, off offset:3072 sc0 sc1" : "=&v"(bx[7]) : "v"(xb2) : "memory");
    }

    // per-lane poll base: this wave's quarter (kt = wv*4+q), batch c
    const unsigned* hq0 = hpub32 + (size_t)(g * 16 + c) * H_ + wv * 128 + q * 32;

    for (int t = 0; t < T_; ++t) {
        // ---- input-gate GEMM (off critical path) ----
        if (use_xsb) {
            asm volatile("s_waitcnt vmcnt(0)" ::: "memory");   // bx arrived (+ prev publish drained)
            __builtin_amdgcn_sched_barrier(0);
        } else {
            const float* xrow = xs + ((size_t)batch * T_ + t) * I_ + q * 8;
#pragma unroll
            for (int kt = 0; kt < 8; ++kt) bx[kt] = ld8_bf(xrow + kt * 32);
        }

        floatx4 accr  = {br[0],  br[1],  br[2],  br[3]};
        floatx4 accz  = {bz[0],  bz[1],  bz[2],  bz[3]};
        floatx4 accni = {bni[0], bni[1], bni[2], bni[3]};
        floatx4 accnh = {0.f, 0.f, 0.f, 0.f};
#pragma unroll
        for (int kt = 0; kt < 8; ++kt) {
            accr  = __builtin_amdgcn_mfma_f32_16x16x32_bf16(wih[0][kt], bx[kt], accr,  0, 0, 0);
            accz  = __builtin_amdgcn_mfma_f32_16x16x32_bf16(wih[1][kt], bx[kt], accz,  0, 0, 0);
            accni = __builtin_amdgcn_mfma_f32_16x16x32_bf16(wih[2][kt], bx[kt], accni, 0, 0, 0);
        }
        __builtin_amdgcn_sched_barrier(0);

        // ---- poll own quarter of tagged h(t): tag==t in every dword ----
        const unsigned tcur = (unsigned)t;
        const unsigned* hb = hq0 + (size_t)(t & 1) * (B_ * H_);
        uintx4 st[8];
        for (;;) {
#pragma unroll
            for (int l = 0; l < 8; ++l)
                asm volatile("global_load_dwordx4 %0, %1, off offset:%2 sc0 sc1"
                             : "=&v"(st[l]) : "v"(hb), "n"(l * 16) : "memory");
            asm volatile("s_waitcnt vmcnt(0)" ::: "memory");
            __builtin_amdgcn_sched_barrier(0);
            unsigned chk = 0;
#pragma unroll
            for (int l = 0; l < 8; ++l) {
                chk |= st[l][0] ^ tcur; chk |= st[l][1] ^ tcur;
                chk |= st[l][2] ^ tcur; chk |= st[l][3] ^ tcur;
            }
            if (__all((chk & 0xffffu) == 0u)) break;
            __builtin_amdgcn_s_sleep(1);
        }

        // ---- pack to bf16 and stage into LDS ----
        char* sw   = (char*)smem + (t & 1) * 20480;
        char* srow = sw + (wv * 4 + q) * 1280 + c * 80;
#pragma unroll
        for (int w = 0; w < 4; ++w) {
            uintx4 pw;
            pw[0] = (st[2*w][0]   >> 16) | (st[2*w][1]   & 0xffff0000u);
            pw[1] = (st[2*w][2]   >> 16) | (st[2*w][3]   & 0xffff0000u);
            pw[2] = (st[2*w+1][0] >> 16) | (st[2*w+1][1] & 0xffff0000u);
            pw[3] = (st[2*w+1][2] >> 16) | (st[2*w+1][3] & 0xffff0000u);
            *(uintx4*)(srow + w * 16) = pw;
        }
        __syncthreads();

        // ---- recurrent GEMM from LDS ----
        const char* srd = sw + c * 80 + q * 16;
#pragma unroll
        for (int kt = 0; kt < 16; ++kt) {
            union { uintx4 u; short8 s; } bh;
            bh.u = *(const uintx4*)(srd + kt * 1280);
            accr  = __builtin_amdgcn_mfma_f32_16x16x32_bf16(whh[0][kt], bh.s, accr,  0, 0, 0);
            accz  = __builtin_amdgcn_mfma_f32_16x16x32_bf16(whh[1][kt], bh.s, accz,  0, 0, 0);
            accnh = __builtin_amdgcn_mfma_f32_16x16x32_bf16(whh[2][kt], bh.s, accnh, 0, 0, 0);
        }

        // ---- gates ----
#pragma unroll
        for (int i = 0; i < 4; ++i) {
            float r = sigf(accr[i]);
            float z = sigf(accz[i]);
            float n = tanh_(accni[i] + r * (accnh[i] + bnn[i]));
            hown[i] = n + z * (hown[i] - n);
        }

        if (t + 1 < T_) {
            // ---- publish own slice as 4 tagged u32 (ONE 16B store, no fences) ----
            unsigned tg = (unsigned)(t + 1);
            uintx4 pq;
            pq[0] = ((unsigned)f2bf(hown[0]) << 16) | tg;
            pq[1] = ((unsigned)f2bf(hown[1]) << 16) | tg;
            pq[2] = ((unsigned)f2bf(hown[2]) << 16) | tg;
            pq[3] = ((unsigned)f2bf(hown[3]) << 16) | tg;
            unsigned* dst = hpub32 + ((size_t)((t + 1) & 1) * B_ + g * 16 + c) * H_ + hbase + q * 4;
            asm volatile("global_store_dwordx4 %0, %1, off sc0 sc1" :: "v"(dst), "v"(pq) : "memory");

            if (use_xsb) {   // prefetch x(t+1); drained by next iter's vmcnt(0)
                const char* xb  = xsb + (((size_t)(t + 1) * NG + g) << 13) + ((q * 16 + c) << 4);
                const char* xb2 = xb + 4096;
                asm volatile("global_load_dwordx4 %0, %1, off sc0 sc1"             : "=&v"(bx[0]) : "v"(xb)  : "memory");
                asm volatile("global_load_dwordx4 %0, %1, off offset:1024 sc0 sc1" : "=&v"(bx[1]) : "v"(xb)  : "memory");
                asm volatile("global_load_dwordx4 %0, %1, off offset:2048 sc0 sc1" : "=&v"(bx[2]) : "v"(xb)  : "memory");
                asm volatile("global_load_dwordx4 %0, %1, off offset:3072 sc0 sc1" : "=&v"(bx[3]) : "v"(xb)  : "memory");
                asm volatile("global_load_dwordx4 %0, %1, off sc0 sc1"             : "=&v"(bx[4]) : "v"(xb2) : "memory");
                asm volatile("global_load_dwordx4 %0, %1, off offset:1024 sc0 sc1" : "=&v"(bx[5]) : "v"(xb2) : "memory");
                asm volatile("global_load_dwordx4 %0, %1, off offset:2048 sc0 sc1" : "=&v"(bx[6]) : "v"(xb2) : "memory");
                asm volatile("global_load_dwordx4 %0, %1, off offset:3072 sc0 sc1" : "=&v"(bx[7]) : "v"(xb2) : "memory");
            }
        }
    }

    // ---- final h (fp32) ----
    floatx4 o = {hown[0], hown[1], hown[2], hown[3]};
    *(floatx4*)(out + (size_t)batch * H_ + hbase + q * 4) = o;
}

extern "C" void kernel_launch(void* const* d_in, const int* in_sizes, int n_in,
                              void* d_out, int out_size, void* d_ws, size_t ws_size,
                              hipStream_t stream) {
    (void)in_sizes; (void)n_in; (void)out_size;
    const float* xs   = (const float*)d_in[0];
    const float* w_ih = (const float*)d_in[1];
    const float* w_hh = (const float*)d_in[2];
    const float* b    = (const float*)d_in[3];
    const float* b_n  = (const float*)d_in[4];
    float* out = (float*)d_out;

    unsigned* flags  = (unsigned*)d_ws;
    unsigned* hpub32 = (unsigned*)((char*)d_ws + HPUB32_OFF);
    char*     xsb    = (char*)d_ws + XSB_OFF;
    const int use_xsb = (ws_size >= (size_t)XSB_OFF + XSB_BYTES) ? 1 : 0;

    // zero cflags + tagged-h double buffer (tag 0 == step 0, h == 0)
    (void)hipMemsetAsync(d_ws, 0, XSB_OFF, stream);

    gru_persist<<<NG * NP, 256, 0, stream>>>(xs, w_ih, w_hh, b, b_n, out,
                                             flags, hpub32, xsb, use_xsb);
}